// Round 9
// baseline (1182.453 us; speedup 1.0000x reference)
//
#include <hip/hip_runtime.h>
#include <hip/hip_bf16.h>
#include <hip/hip_fp16.h>
#include <cstdint>

#define HH 128
#define WW 128
#define CC 64
#define BB 16
#define PLANE (HH*WW)
// T workspace layout: half Th[b][row][ci][col]  (fp16, "[B][H][C][W]").
// fp16 halves k_mix's dominant traffic term (T is re-read 8x by the co-groups
// of each block; v1-structure measured 5.2 TB/s on 664 MB -> BW-bound).
// T magnitudes are ~1-10 -> fp16 (10 mantissa bits) adds ~4x LESS error than
// the bf16 h-intermediates already used inside k_dwsum.
#define TROW   8192       // halves per (b,row): 64 ci * 128 col
#define TBATCH (128*TROW) // halves per batch

// k_dwsum LDS layout (two-pass xbuf -> 39552 B -> 4 blocks/CU).
#define XS_STR    52
#define XRAW_STR  60
#define XSTH_H    8736    // half-index of xsTh   (= 4368 floats * 2)
#define H7_H      11328   // half-index of h7T    (= 5664 floats * 2)
#define UNION_F   7072    // float-index of xbuf
#define H11_H     14144   // half-index of h11T   (inside union)
#define H21_H     16960   // half-index of h21T   (inside union)
#define SMEM_FLOATS 9888  // 39552 B -> 4 blocks/CU

__device__ __forceinline__ float lo16(unsigned int u) {
  return __uint_as_float(u << 16);
}
__device__ __forceinline__ float hi16(unsigned int u) {
  return __uint_as_float(u & 0xffff0000u);
}

// A2 half-pass: U = x + avg3 + max3 for rg in [rg_lo, rg_lo+14).
__device__ __forceinline__ void phase_a2_half(
    float* sm, __hip_bfloat16* hb, const float* xbuf, int tid, int tR0,
    int tC0, int rg_lo, int roff) {
  __hip_bfloat16* xsTh = hb + XSTH_H;
  for (int i = tid; i < 14 * 13; i += 256) {
    int rg = rg_lo + (i % 14);           // lane-consecutive row group
    int jj = i / 14;
    int rr0 = rg * 3;                    // xs rows rr0..rr0+2
    const float* rp = xbuf + (rr0 - roff) * XRAW_STR + jj * 4;
    float w[5][8];
    #pragma unroll
    for (int k = 0; k < 5; ++k) {
      float4 a = *(const float4*)(rp + k * XRAW_STR);
      float4 b = *(const float4*)(rp + k * XRAW_STR + 4);
      w[k][0] = a.x; w[k][1] = a.y; w[k][2] = a.z; w[k][3] = a.w;
      w[k][4] = b.x; w[k][5] = b.y; w[k][6] = b.z; w[k][7] = b.w;
    }
    int gc0 = tC0 + jj * 4 - 12;
    bool cv[7];
    #pragma unroll
    for (int p = 1; p <= 6; ++p) cv[p] = (unsigned)(gc0 + p) < 128u;

    #pragma unroll
    for (int k = 0; k < 3; ++k) {
      int rr = rr0 + k;
      int gr = tR0 + rr - 10;
      bool rv0 = (unsigned)(gr - 1) < 128u;
      bool rv1 = (unsigned)(gr) < 128u;
      bool rv2 = (unsigned)(gr + 1) < 128u;
      float M0[7], M1[7], M2[7];
      #pragma unroll
      for (int p = 1; p <= 6; ++p) {
        M0[p] = (rv0 && cv[p]) ? w[k][p] : -3.402823466e38f;
        M1[p] = (rv1 && cv[p]) ? w[k + 1][p] : -3.402823466e38f;
        M2[p] = (rv2 && cv[p]) ? w[k + 2][p] : -3.402823466e38f;
      }
      float uq[4];
      #pragma unroll
      for (int q = 0; q < 4; ++q) {
        float s = w[k][q + 1] + w[k][q + 2] + w[k][q + 3] + w[k + 1][q + 1] +
                  w[k + 1][q + 2] + w[k + 1][q + 3] + w[k + 2][q + 1] +
                  w[k + 2][q + 2] + w[k + 2][q + 3];
        float m = fmaxf(
            fmaxf(fmaxf(M0[q + 1], M0[q + 2]), fmaxf(M0[q + 3], M1[q + 1])),
            fmaxf(fmaxf(M1[q + 2], M1[q + 3]),
                  fmaxf(fmaxf(M2[q + 1], M2[q + 2]), M2[q + 3])));
        float val = w[k + 1][q + 2] + s * (1.f / 9.f) + m;
        bool vo = rv1 && ((unsigned)(gc0 + q + 2) < 128u);
        uq[q] = vo ? val : 0.f;
      }
      *(float4*)(sm + rr * XS_STR + jj * 4) =
          make_float4(uq[0], uq[1], uq[2], uq[3]);
      int rt = rr - 8;                   // xsTh row (tile row -2..65)
      if ((unsigned)rt < 68u) {
        #pragma unroll
        for (int q = 0; q < 4; ++q) {
          int ct = jj * 4 + q - 8;       // xsTh col (tile col -2..33)
          if ((unsigned)ct < 36u)
            xsTh[ct * 72 + rt] = __float2bfloat16(uq[q]);
        }
      }
    }
  }
}

__global__ __launch_bounds__(256, 4) void k_dwsum(
    const float* __restrict__ x, __half* __restrict__ T,
    const float* __restrict__ w55, const float* __restrict__ b55,
    const float* __restrict__ w17_0, const float* __restrict__ b17_0,
    const float* __restrict__ w17_1, const float* __restrict__ b17_1,
    const float* __restrict__ w111_0, const float* __restrict__ b111_0,
    const float* __restrict__ w111_1, const float* __restrict__ b111_1,
    const float* __restrict__ w211_0, const float* __restrict__ b211_0,
    const float* __restrict__ w211_1, const float* __restrict__ b211_1) {
  __shared__ float sm[SMEM_FLOATS];
  __hip_bfloat16* hb = (__hip_bfloat16*)sm;

  const int bid = blockIdx.x;
  const int pl = bid >> 3;
  const int t = bid & 7;
  const int tR0 = (t >> 2) * 64;
  const int tC0 = (t & 3) * 32;
  const int ch = pl & (CC - 1);
  const int bb2 = pl >> 6;               // batch index
  const float* xp = x + (size_t)pl * PLANE;
  // Th[b][row][ch][col]: base for this (b, ch)
  __half* Tp = T + (size_t)bb2 * TBATCH + (size_t)ch * 128;
  const int tid = threadIdx.x;

  float* xbuf = sm + UNION_F;
  const int base_r = tR0 - 11, base_c = tC0 - 12;

  // ---- phase A pass 1: raw rows 0..43 of halo tile ----
  for (int i = tid; i < 44 * 14; i += 256) {
    int rr = i / 14;
    int jj = i - rr * 14;
    int gr = base_r + rr;
    int gc = base_c + jj * 4;
    float4 v = make_float4(0.f, 0.f, 0.f, 0.f);
    if ((unsigned)gr < 128u && (unsigned)gc < 128u)
      v = *(const float4*)(xp + gr * WW + gc);
    *(float4*)(xbuf + rr * XRAW_STR + jj * 4) = v;
  }
  __syncthreads();
  phase_a2_half(sm, hb, xbuf, tid, tR0, tC0, 0, 0);   // xs rows 0..41
  __syncthreads();
  // ---- phase A pass 2: raw rows 42..85 ----
  for (int i = tid; i < 44 * 14; i += 256) {
    int rr = i / 14;
    int jj = i - rr * 14;
    int gr = base_r + 42 + rr;
    int gc = base_c + jj * 4;
    float4 v = make_float4(0.f, 0.f, 0.f, 0.f);
    if ((unsigned)gr < 128u && (unsigned)gc < 128u)
      v = *(const float4*)(xp + gr * WW + gc);
    *(float4*)(xbuf + rr * XRAW_STR + jj * 4) = v;
  }
  __syncthreads();
  phase_a2_half(sm, hb, xbuf, tid, tR0, tC0, 14, 42); // xs rows 42..83

  float k7[7], k11[11], k21[21];
  #pragma unroll
  for (int i = 0; i < 7; ++i) k7[i] = w17_0[ch * 7 + i];
  #pragma unroll
  for (int i = 0; i < 11; ++i) k11[i] = w111_0[ch * 11 + i];
  #pragma unroll
  for (int i = 0; i < 21; ++i) k21[i] = w211_0[ch * 21 + i];
  float bb7 = 3.f * b17_0[ch];
  float bb11 = 3.f * b111_0[ch];
  float bb21 = 3.f * b211_0[ch];

  __syncthreads();

  // ---- phase B: horizontal convs; bf16 transposed stores (lane-consec rr) --
  for (int it = tid; it < 84 * 4; it += 256) {
    int rr = it % 84;
    int cg = it / 84;                    // output tile cols cg*8..+7
    float w[28];
    const float* xr = sm + rr * XS_STR + cg * 8;
    #pragma unroll
    for (int j = 0; j < 7; ++j) {
      float4 v = *(const float4*)(xr + 4 * j);
      w[4 * j] = v.x; w[4 * j + 1] = v.y; w[4 * j + 2] = v.z; w[4 * j + 3] = v.w;
    }
    int gr = tR0 + rr - 10;
    bool rv = (unsigned)gr < 128u;
    bool v11r = (rr >= 5) && (rr <= 78);
    bool v7r = (rr >= 7) && (rr <= 76);
    #pragma unroll
    for (int j = 0; j < 8; ++j) {
      float a21 = bb21, a11 = bb11, a7 = bb7;
      #pragma unroll
      for (int d = 0; d < 21; ++d) a21 += k21[d] * w[j + d];
      #pragma unroll
      for (int d = 0; d < 11; ++d) a11 += k11[d] * w[j + 5 + d];
      #pragma unroll
      for (int d = 0; d < 7; ++d) a7 += k7[d] * w[j + 7 + d];
      int c = cg * 8 + j;
      hb[H21_H + c * 88 + rr] = __float2bfloat16(rv ? a21 : 0.f);
      if (v11r) hb[H11_H + c * 88 + rr - 5] = __float2bfloat16(rv ? a11 : 0.f);
      if (v7r) hb[H7_H + c * 88 + rr - 7] = __float2bfloat16(rv ? a7 : 0.f);
    }
  }

  float v7a[7], v11a[11], v21a[21], w5a[25];
  #pragma unroll
  for (int i = 0; i < 7; ++i) v7a[i] = w17_1[ch * 7 + i];
  #pragma unroll
  for (int i = 0; i < 11; ++i) v11a[i] = w111_1[ch * 11 + i];
  #pragma unroll
  for (int i = 0; i < 21; ++i) v21a[i] = w211_1[ch * 21 + i];
  #pragma unroll
  for (int i = 0; i < 25; ++i) w5a[i] = w55[ch * 25 + i];
  float bsum = 3.f * (b55[ch] + b17_1[ch] + b111_1[ch] + b211_1[ch]);

  __syncthreads();

  // ---- phase C: vertical convs + 5x5; 8 rows/thread along a column ----
  {
    int c = tid & 31;
    int r0 = (tid >> 5) * 8;
    float acc[8];
    #pragma unroll
    for (int j = 0; j < 8; ++j) acc[j] = bsum;

    float A[28];
    {  // h21: indices r0..r0+27 (28 halves)
      const unsigned* p = (const unsigned*)&hb[H21_H + c * 88 + r0];
      uint4 q0 = *(const uint4*)p;
      uint4 q1 = *(const uint4*)(p + 4);
      uint4 q2 = *(const uint4*)(p + 8);
      uint2 q3 = *(const uint2*)(p + 12);
      A[0]=lo16(q0.x);A[1]=hi16(q0.x);A[2]=lo16(q0.y);A[3]=hi16(q0.y);
      A[4]=lo16(q0.z);A[5]=hi16(q0.z);A[6]=lo16(q0.w);A[7]=hi16(q0.w);
      A[8]=lo16(q1.x);A[9]=hi16(q1.x);A[10]=lo16(q1.y);A[11]=hi16(q1.y);
      A[12]=lo16(q1.z);A[13]=hi16(q1.z);A[14]=lo16(q1.w);A[15]=hi16(q1.w);
      A[16]=lo16(q2.x);A[17]=hi16(q2.x);A[18]=lo16(q2.y);A[19]=hi16(q2.y);
      A[20]=lo16(q2.z);A[21]=hi16(q2.z);A[22]=lo16(q2.w);A[23]=hi16(q2.w);
      A[24]=lo16(q3.x);A[25]=hi16(q3.x);A[26]=lo16(q3.y);A[27]=hi16(q3.y);
      #pragma unroll
      for (int d = 0; d < 21; ++d)
        #pragma unroll
        for (int j = 0; j < 8; ++j) acc[j] += v21a[d] * A[d + j];
    }
    {  // h11: indices r0..r0+17 (18 halves, read 20)
      const unsigned* p = (const unsigned*)&hb[H11_H + c * 88 + r0];
      uint4 q0 = *(const uint4*)p;
      uint4 q1 = *(const uint4*)(p + 4);
      uint2 q2 = *(const uint2*)(p + 8);
      A[0]=lo16(q0.x);A[1]=hi16(q0.x);A[2]=lo16(q0.y);A[3]=hi16(q0.y);
      A[4]=lo16(q0.z);A[5]=hi16(q0.z);A[6]=lo16(q0.w);A[7]=hi16(q0.w);
      A[8]=lo16(q1.x);A[9]=hi16(q1.x);A[10]=lo16(q1.y);A[11]=hi16(q1.y);
      A[12]=lo16(q1.z);A[13]=hi16(q1.z);A[14]=lo16(q1.w);A[15]=hi16(q1.w);
      A[16]=lo16(q2.x);A[17]=hi16(q2.x);
      #pragma unroll
      for (int d = 0; d < 11; ++d)
        #pragma unroll
        for (int j = 0; j < 8; ++j) acc[j] += v11a[d] * A[d + j];
    }
    {  // h7: indices r0..r0+13 (14 halves, read 16)
      const unsigned* p = (const unsigned*)&hb[H7_H + c * 88 + r0];
      uint4 q0 = *(const uint4*)p;
      uint4 q1 = *(const uint4*)(p + 4);
      A[0]=lo16(q0.x);A[1]=hi16(q0.x);A[2]=lo16(q0.y);A[3]=hi16(q0.y);
      A[4]=lo16(q0.z);A[5]=hi16(q0.z);A[6]=lo16(q0.w);A[7]=hi16(q0.w);
      A[8]=lo16(q1.x);A[9]=hi16(q1.x);A[10]=lo16(q1.y);A[11]=hi16(q1.y);
      A[12]=lo16(q1.z);A[13]=hi16(q1.z);
      #pragma unroll
      for (int d = 0; d < 7; ++d)
        #pragma unroll
        for (int j = 0; j < 8; ++j) acc[j] += v7a[d] * A[d + j];
    }
    {  // 5x5 from bf16 transposed U: cols c..c+4, rows r0..r0+11
      #pragma unroll
      for (int dc = 0; dc < 5; ++dc) {
        const unsigned* p = (const unsigned*)&hb[XSTH_H + (c + dc) * 72 + r0];
        uint4 q0 = *(const uint4*)p;
        uint2 q1 = *(const uint2*)(p + 4);
        float X[12];
        X[0]=lo16(q0.x);X[1]=hi16(q0.x);X[2]=lo16(q0.y);X[3]=hi16(q0.y);
        X[4]=lo16(q0.z);X[5]=hi16(q0.z);X[6]=lo16(q0.w);X[7]=hi16(q0.w);
        X[8]=lo16(q1.x);X[9]=hi16(q1.x);X[10]=lo16(q1.y);X[11]=hi16(q1.y);
        #pragma unroll
        for (int dr = 0; dr < 5; ++dr)
          #pragma unroll
          for (int j = 0; j < 8; ++j) acc[j] += w5a[dr * 5 + dc] * X[j + dr];
      }
    }
    // Th[b][row][ch][col]: fp16 store (64 B-contiguous per 32-lane group).
    #pragma unroll
    for (int j = 0; j < 8; ++j)
      Tp[(size_t)(tR0 + r0 + j) * TROW + tC0 + c] = __float2half(acc[j]);
  }
}

// ---------------------------------------------------------------------------
// k_mix v9: out = (W11 . T + 3*b11) * x.  EXACT v1 streaming skeleton (64 x
// 16-B T-loads/thread, 3-slot 2-chunk-deep register ring, no k-loop barriers,
// plain __launch_bounds__(256)) -- v1 measured 5.2 TB/s on 664 MB, i.e.
// HBM-BW-bound at its inflated traffic. fp16 T halves the dominant term:
// 8x33.5 + 64 + 64 = 396 MB.  Thread = 8 px x 8 co (16-B load = 8 halves),
// block = 256 px x 64 co, grid 1024.
// ---------------------------------------------------------------------------
__device__ __forceinline__ float2 h2f2(unsigned u) {
  return __half22float2(*reinterpret_cast<const __half2*>(&u));
}

__global__ __launch_bounds__(256) void k_mix(const __half* __restrict__ T,
                                             const float* __restrict__ x,
                                             const float* __restrict__ w11,
                                             const float* __restrict__ b11,
                                             float* __restrict__ out) {
  __shared__ float Wt[64 * 68];            // [ci][co], stride 68
  int bid = blockIdx.x;
  int b = bid >> 6;
  int rp = bid & 63;                       // row pair: rows 2rp, 2rp+1
  int px0 = rp * 256;
  int tid = threadIdx.x;

  for (int i = tid; i < 4096; i += 256) {
    int co = i >> 6, ci = i & 63;
    Wt[ci * 68 + co] = w11[i];
  }
  __syncthreads();

  int pxg = tid & 31;                      // 32 groups x 8 px = 256 px
  int cog = tid >> 5;                      // 8 groups x 8 co
  // Th[b][row][ci][col]; a thread's 8 px sit in one row.
  const __half* Tb = T + (size_t)b * TBATCH +
                     (size_t)(2 * rp + (pxg >> 4)) * TROW + (pxg & 15) * 8;
  const float* wp = Wt + cog * 8;

  float acc[8][8];
  #pragma unroll
  for (int a = 0; a < 8; ++a)
    #pragma unroll
    for (int p = 0; p < 8; ++p) acc[a][p] = 0.f;

  uint4 tb[3][4];
  #pragma unroll
  for (int kk = 0; kk < 4; ++kk)
    tb[0][kk] = *(const uint4*)(Tb + (size_t)kk * 128);
  #pragma unroll
  for (int kk = 0; kk < 4; ++kk)
    tb[1][kk] = *(const uint4*)(Tb + (size_t)(4 + kk) * 128);

  #pragma unroll
  for (int kc = 0; kc < 16; ++kc) {
    const int cur = kc % 3;
    if (kc < 14) {
      const int nxt = (kc + 2) % 3;
      #pragma unroll
      for (int kk = 0; kk < 4; ++kk)
        tb[nxt][kk] =
            *(const uint4*)(Tb + (size_t)((kc + 2) * 4 + kk) * 128);
    }
    #pragma unroll
    for (int kk = 0; kk < 4; ++kk) {
      int k = kc * 4 + kk;
      float4 q0 = *(const float4*)(wp + k * 68);
      float4 q1 = *(const float4*)(wp + k * 68 + 4);
      float wf[8] = {q0.x, q0.y, q0.z, q0.w, q1.x, q1.y, q1.z, q1.w};
      uint4 tq = tb[cur][kk];
      float2 t0 = h2f2(tq.x), t1 = h2f2(tq.y), t2 = h2f2(tq.z),
             t3 = h2f2(tq.w);
      float tv[8] = {t0.x, t0.y, t1.x, t1.y, t2.x, t2.y, t3.x, t3.y};
      #pragma unroll
      for (int a = 0; a < 8; ++a)
        #pragma unroll
        for (int p = 0; p < 8; ++p) acc[a][p] += wf[a] * tv[p];
    }
  }

  const float* xb = x + (size_t)b * (CC * PLANE) + px0 + pxg * 8;
  float* ob = out + (size_t)b * (CC * PLANE) + px0 + pxg * 8;
  #pragma unroll
  for (int a = 0; a < 8; ++a) {
    int co = cog * 8 + a;
    float bb = 3.f * b11[co];
    float4 xv0 = *(const float4*)(xb + (size_t)co * PLANE);
    float4 xv1 = *(const float4*)(xb + (size_t)co * PLANE + 4);
    float4 o0, o1;
    o0.x = (acc[a][0] + bb) * xv0.x;
    o0.y = (acc[a][1] + bb) * xv0.y;
    o0.z = (acc[a][2] + bb) * xv0.z;
    o0.w = (acc[a][3] + bb) * xv0.w;
    o1.x = (acc[a][4] + bb) * xv1.x;
    o1.y = (acc[a][5] + bb) * xv1.y;
    o1.z = (acc[a][6] + bb) * xv1.z;
    o1.w = (acc[a][7] + bb) * xv1.w;
    *(float4*)(ob + (size_t)co * PLANE) = o0;
    *(float4*)(ob + (size_t)co * PLANE + 4) = o1;
  }
}

extern "C" void kernel_launch(void* const* d_in, const int* in_sizes, int n_in,
                              void* d_out, int out_size, void* d_ws,
                              size_t ws_size, hipStream_t stream) {
  const float* x = (const float*)d_in[0];
  const float* w55 = (const float*)d_in[1];
  const float* b55 = (const float*)d_in[2];
  const float* w17_0 = (const float*)d_in[3];
  const float* b17_0 = (const float*)d_in[4];
  const float* w17_1 = (const float*)d_in[5];
  const float* b17_1 = (const float*)d_in[6];
  const float* w111_0 = (const float*)d_in[7];
  const float* b111_0 = (const float*)d_in[8];
  const float* w111_1 = (const float*)d_in[9];
  const float* b111_1 = (const float*)d_in[10];
  const float* w211_0 = (const float*)d_in[11];
  const float* b211_0 = (const float*)d_in[12];
  const float* w211_1 = (const float*)d_in[13];
  const float* b211_1 = (const float*)d_in[14];
  const float* w11 = (const float*)d_in[15];
  const float* b11 = (const float*)d_in[16];
  float* outp = (float*)d_out;

  __half* T = (__half*)d_ws;               // Th[16][128][64][128] = 32 MB

  k_dwsum<<<BB * CC * 8, 256, 0, stream>>>(
      x, T, w55, b55, w17_0, b17_0, w17_1, b17_1, w111_0, b111_0, w111_1,
      b111_1, w211_0, b211_0, w211_1, b211_1);
  k_mix<<<BB * 64, 256, 0, stream>>>(T, x, w11, b11, outp);
}

// Round 10
// 286.027 us; speedup vs baseline: 4.1341x; 4.1341x over previous
//
#include <hip/hip_runtime.h>
#include <hip/hip_bf16.h>
#include <hip/hip_fp16.h>
#include <cstdint>

#define HH 128
#define WW 128
#define CC 64
#define BB 16
#define PLANE (HH*WW)
// T workspace layout: half Th[b][row][ci][col]  (fp16, "[B][H][C][W]").
// fp16 T verified round 9: absmax unchanged (0.0625). Halves k_mix's
// dominant traffic term at IDENTICAL instruction structure to v1 (the
// proven 5.2 TB/s BW-bound streaming skeleton).
#define TROW   8192       // halves per (b,row): 64 ci * 128 col
#define TBATCH (128*TROW) // halves per batch

// k_dwsum LDS layout (two-pass xbuf -> 39552 B -> 4 blocks/CU).
#define XS_STR    52
#define XRAW_STR  60
#define XSTH_H    8736    // half-index of xsTh   (= 4368 floats * 2)
#define H7_H      11328   // half-index of h7T    (= 5664 floats * 2)
#define UNION_F   7072    // float-index of xbuf
#define H11_H     14144   // half-index of h11T   (inside union)
#define H21_H     16960   // half-index of h21T   (inside union)
#define SMEM_FLOATS 9888  // 39552 B -> 4 blocks/CU

__device__ __forceinline__ float lo16(unsigned int u) {
  return __uint_as_float(u << 16);
}
__device__ __forceinline__ float hi16(unsigned int u) {
  return __uint_as_float(u & 0xffff0000u);
}

// A2 half-pass: U = x + avg3 + max3 for rg in [rg_lo, rg_lo+14).
__device__ __forceinline__ void phase_a2_half(
    float* sm, __hip_bfloat16* hb, const float* xbuf, int tid, int tR0,
    int tC0, int rg_lo, int roff) {
  __hip_bfloat16* xsTh = hb + XSTH_H;
  for (int i = tid; i < 14 * 13; i += 256) {
    int rg = rg_lo + (i % 14);           // lane-consecutive row group
    int jj = i / 14;
    int rr0 = rg * 3;                    // xs rows rr0..rr0+2
    const float* rp = xbuf + (rr0 - roff) * XRAW_STR + jj * 4;
    float w[5][8];
    #pragma unroll
    for (int k = 0; k < 5; ++k) {
      float4 a = *(const float4*)(rp + k * XRAW_STR);
      float4 b = *(const float4*)(rp + k * XRAW_STR + 4);
      w[k][0] = a.x; w[k][1] = a.y; w[k][2] = a.z; w[k][3] = a.w;
      w[k][4] = b.x; w[k][5] = b.y; w[k][6] = b.z; w[k][7] = b.w;
    }
    int gc0 = tC0 + jj * 4 - 12;
    bool cv[7];
    #pragma unroll
    for (int p = 1; p <= 6; ++p) cv[p] = (unsigned)(gc0 + p) < 128u;

    #pragma unroll
    for (int k = 0; k < 3; ++k) {
      int rr = rr0 + k;
      int gr = tR0 + rr - 10;
      bool rv0 = (unsigned)(gr - 1) < 128u;
      bool rv1 = (unsigned)(gr) < 128u;
      bool rv2 = (unsigned)(gr + 1) < 128u;
      float M0[7], M1[7], M2[7];
      #pragma unroll
      for (int p = 1; p <= 6; ++p) {
        M0[p] = (rv0 && cv[p]) ? w[k][p] : -3.402823466e38f;
        M1[p] = (rv1 && cv[p]) ? w[k + 1][p] : -3.402823466e38f;
        M2[p] = (rv2 && cv[p]) ? w[k + 2][p] : -3.402823466e38f;
      }
      float uq[4];
      #pragma unroll
      for (int q = 0; q < 4; ++q) {
        float s = w[k][q + 1] + w[k][q + 2] + w[k][q + 3] + w[k + 1][q + 1] +
                  w[k + 1][q + 2] + w[k + 1][q + 3] + w[k + 2][q + 1] +
                  w[k + 2][q + 2] + w[k + 2][q + 3];
        float m = fmaxf(
            fmaxf(fmaxf(M0[q + 1], M0[q + 2]), fmaxf(M0[q + 3], M1[q + 1])),
            fmaxf(fmaxf(M1[q + 2], M1[q + 3]),
                  fmaxf(fmaxf(M2[q + 1], M2[q + 2]), M2[q + 3])));
        float val = w[k + 1][q + 2] + s * (1.f / 9.f) + m;
        bool vo = rv1 && ((unsigned)(gc0 + q + 2) < 128u);
        uq[q] = vo ? val : 0.f;
      }
      *(float4*)(sm + rr * XS_STR + jj * 4) =
          make_float4(uq[0], uq[1], uq[2], uq[3]);
      int rt = rr - 8;                   // xsTh row (tile row -2..65)
      if ((unsigned)rt < 68u) {
        #pragma unroll
        for (int q = 0; q < 4; ++q) {
          int ct = jj * 4 + q - 8;       // xsTh col (tile col -2..33)
          if ((unsigned)ct < 36u)
            xsTh[ct * 72 + rt] = __float2bfloat16(uq[q]);
        }
      }
    }
  }
}

__global__ __launch_bounds__(256, 4) void k_dwsum(
    const float* __restrict__ x, __half* __restrict__ T,
    const float* __restrict__ w55, const float* __restrict__ b55,
    const float* __restrict__ w17_0, const float* __restrict__ b17_0,
    const float* __restrict__ w17_1, const float* __restrict__ b17_1,
    const float* __restrict__ w111_0, const float* __restrict__ b111_0,
    const float* __restrict__ w111_1, const float* __restrict__ b111_1,
    const float* __restrict__ w211_0, const float* __restrict__ b211_0,
    const float* __restrict__ w211_1, const float* __restrict__ b211_1) {
  __shared__ float sm[SMEM_FLOATS];
  __hip_bfloat16* hb = (__hip_bfloat16*)sm;

  const int bid = blockIdx.x;
  const int pl = bid >> 3;
  const int t = bid & 7;
  const int tR0 = (t >> 2) * 64;
  const int tC0 = (t & 3) * 32;
  const int ch = pl & (CC - 1);
  const int bb2 = pl >> 6;               // batch index
  const float* xp = x + (size_t)pl * PLANE;
  // Th[b][row][ch][col]: base for this (b, ch)
  __half* Tp = T + (size_t)bb2 * TBATCH + (size_t)ch * 128;
  const int tid = threadIdx.x;

  float* xbuf = sm + UNION_F;
  const int base_r = tR0 - 11, base_c = tC0 - 12;

  // ---- phase A pass 1: raw rows 0..43 of halo tile ----
  for (int i = tid; i < 44 * 14; i += 256) {
    int rr = i / 14;
    int jj = i - rr * 14;
    int gr = base_r + rr;
    int gc = base_c + jj * 4;
    float4 v = make_float4(0.f, 0.f, 0.f, 0.f);
    if ((unsigned)gr < 128u && (unsigned)gc < 128u)
      v = *(const float4*)(xp + gr * WW + gc);
    *(float4*)(xbuf + rr * XRAW_STR + jj * 4) = v;
  }
  __syncthreads();
  phase_a2_half(sm, hb, xbuf, tid, tR0, tC0, 0, 0);   // xs rows 0..41
  __syncthreads();
  // ---- phase A pass 2: raw rows 42..85 ----
  for (int i = tid; i < 44 * 14; i += 256) {
    int rr = i / 14;
    int jj = i - rr * 14;
    int gr = base_r + 42 + rr;
    int gc = base_c + jj * 4;
    float4 v = make_float4(0.f, 0.f, 0.f, 0.f);
    if ((unsigned)gr < 128u && (unsigned)gc < 128u)
      v = *(const float4*)(xp + gr * WW + gc);
    *(float4*)(xbuf + rr * XRAW_STR + jj * 4) = v;
  }
  __syncthreads();
  phase_a2_half(sm, hb, xbuf, tid, tR0, tC0, 14, 42); // xs rows 42..83

  float k7[7], k11[11], k21[21];
  #pragma unroll
  for (int i = 0; i < 7; ++i) k7[i] = w17_0[ch * 7 + i];
  #pragma unroll
  for (int i = 0; i < 11; ++i) k11[i] = w111_0[ch * 11 + i];
  #pragma unroll
  for (int i = 0; i < 21; ++i) k21[i] = w211_0[ch * 21 + i];
  float bb7 = 3.f * b17_0[ch];
  float bb11 = 3.f * b111_0[ch];
  float bb21 = 3.f * b211_0[ch];

  __syncthreads();

  // ---- phase B: horizontal convs; bf16 transposed stores (lane-consec rr) --
  for (int it = tid; it < 84 * 4; it += 256) {
    int rr = it % 84;
    int cg = it / 84;                    // output tile cols cg*8..+7
    float w[28];
    const float* xr = sm + rr * XS_STR + cg * 8;
    #pragma unroll
    for (int j = 0; j < 7; ++j) {
      float4 v = *(const float4*)(xr + 4 * j);
      w[4 * j] = v.x; w[4 * j + 1] = v.y; w[4 * j + 2] = v.z; w[4 * j + 3] = v.w;
    }
    int gr = tR0 + rr - 10;
    bool rv = (unsigned)gr < 128u;
    bool v11r = (rr >= 5) && (rr <= 78);
    bool v7r = (rr >= 7) && (rr <= 76);
    #pragma unroll
    for (int j = 0; j < 8; ++j) {
      float a21 = bb21, a11 = bb11, a7 = bb7;
      #pragma unroll
      for (int d = 0; d < 21; ++d) a21 += k21[d] * w[j + d];
      #pragma unroll
      for (int d = 0; d < 11; ++d) a11 += k11[d] * w[j + 5 + d];
      #pragma unroll
      for (int d = 0; d < 7; ++d) a7 += k7[d] * w[j + 7 + d];
      int c = cg * 8 + j;
      hb[H21_H + c * 88 + rr] = __float2bfloat16(rv ? a21 : 0.f);
      if (v11r) hb[H11_H + c * 88 + rr - 5] = __float2bfloat16(rv ? a11 : 0.f);
      if (v7r) hb[H7_H + c * 88 + rr - 7] = __float2bfloat16(rv ? a7 : 0.f);
    }
  }

  float v7a[7], v11a[11], v21a[21], w5a[25];
  #pragma unroll
  for (int i = 0; i < 7; ++i) v7a[i] = w17_1[ch * 7 + i];
  #pragma unroll
  for (int i = 0; i < 11; ++i) v11a[i] = w111_1[ch * 11 + i];
  #pragma unroll
  for (int i = 0; i < 21; ++i) v21a[i] = w211_1[ch * 21 + i];
  #pragma unroll
  for (int i = 0; i < 25; ++i) w5a[i] = w55[ch * 25 + i];
  float bsum = 3.f * (b55[ch] + b17_1[ch] + b111_1[ch] + b211_1[ch]);

  __syncthreads();

  // ---- phase C: vertical convs + 5x5; 8 rows/thread along a column ----
  {
    int c = tid & 31;
    int r0 = (tid >> 5) * 8;
    float acc[8];
    #pragma unroll
    for (int j = 0; j < 8; ++j) acc[j] = bsum;

    float A[28];
    {  // h21: indices r0..r0+27 (28 halves)
      const unsigned* p = (const unsigned*)&hb[H21_H + c * 88 + r0];
      uint4 q0 = *(const uint4*)p;
      uint4 q1 = *(const uint4*)(p + 4);
      uint4 q2 = *(const uint4*)(p + 8);
      uint2 q3 = *(const uint2*)(p + 12);
      A[0]=lo16(q0.x);A[1]=hi16(q0.x);A[2]=lo16(q0.y);A[3]=hi16(q0.y);
      A[4]=lo16(q0.z);A[5]=hi16(q0.z);A[6]=lo16(q0.w);A[7]=hi16(q0.w);
      A[8]=lo16(q1.x);A[9]=hi16(q1.x);A[10]=lo16(q1.y);A[11]=hi16(q1.y);
      A[12]=lo16(q1.z);A[13]=hi16(q1.z);A[14]=lo16(q1.w);A[15]=hi16(q1.w);
      A[16]=lo16(q2.x);A[17]=hi16(q2.x);A[18]=lo16(q2.y);A[19]=hi16(q2.y);
      A[20]=lo16(q2.z);A[21]=hi16(q2.z);A[22]=lo16(q2.w);A[23]=hi16(q2.w);
      A[24]=lo16(q3.x);A[25]=hi16(q3.x);A[26]=lo16(q3.y);A[27]=hi16(q3.y);
      #pragma unroll
      for (int d = 0; d < 21; ++d)
        #pragma unroll
        for (int j = 0; j < 8; ++j) acc[j] += v21a[d] * A[d + j];
    }
    {  // h11: indices r0..r0+17 (18 halves, read 20)
      const unsigned* p = (const unsigned*)&hb[H11_H + c * 88 + r0];
      uint4 q0 = *(const uint4*)p;
      uint4 q1 = *(const uint4*)(p + 4);
      uint2 q2 = *(const uint2*)(p + 8);
      A[0]=lo16(q0.x);A[1]=hi16(q0.x);A[2]=lo16(q0.y);A[3]=hi16(q0.y);
      A[4]=lo16(q0.z);A[5]=hi16(q0.z);A[6]=lo16(q0.w);A[7]=hi16(q0.w);
      A[8]=lo16(q1.x);A[9]=hi16(q1.x);A[10]=lo16(q1.y);A[11]=hi16(q1.y);
      A[12]=lo16(q1.z);A[13]=hi16(q1.z);A[14]=lo16(q1.w);A[15]=hi16(q1.w);
      A[16]=lo16(q2.x);A[17]=hi16(q2.x);
      #pragma unroll
      for (int d = 0; d < 11; ++d)
        #pragma unroll
        for (int j = 0; j < 8; ++j) acc[j] += v11a[d] * A[d + j];
    }
    {  // h7: indices r0..r0+13 (14 halves, read 16)
      const unsigned* p = (const unsigned*)&hb[H7_H + c * 88 + r0];
      uint4 q0 = *(const uint4*)p;
      uint4 q1 = *(const uint4*)(p + 4);
      A[0]=lo16(q0.x);A[1]=hi16(q0.x);A[2]=lo16(q0.y);A[3]=hi16(q0.y);
      A[4]=lo16(q0.z);A[5]=hi16(q0.z);A[6]=lo16(q0.w);A[7]=hi16(q0.w);
      A[8]=lo16(q1.x);A[9]=hi16(q1.x);A[10]=lo16(q1.y);A[11]=hi16(q1.y);
      A[12]=lo16(q1.z);A[13]=hi16(q1.z);
      #pragma unroll
      for (int d = 0; d < 7; ++d)
        #pragma unroll
        for (int j = 0; j < 8; ++j) acc[j] += v7a[d] * A[d + j];
    }
    {  // 5x5 from bf16 transposed U: cols c..c+4, rows r0..r0+11
      #pragma unroll
      for (int dc = 0; dc < 5; ++dc) {
        const unsigned* p = (const unsigned*)&hb[XSTH_H + (c + dc) * 72 + r0];
        uint4 q0 = *(const uint4*)p;
        uint2 q1 = *(const uint2*)(p + 4);
        float X[12];
        X[0]=lo16(q0.x);X[1]=hi16(q0.x);X[2]=lo16(q0.y);X[3]=hi16(q0.y);
        X[4]=lo16(q0.z);X[5]=hi16(q0.z);X[6]=lo16(q0.w);X[7]=hi16(q0.w);
        X[8]=lo16(q1.x);X[9]=hi16(q1.x);X[10]=lo16(q1.y);X[11]=hi16(q1.y);
        #pragma unroll
        for (int dr = 0; dr < 5; ++dr)
          #pragma unroll
          for (int j = 0; j < 8; ++j) acc[j] += w5a[dr * 5 + dc] * X[j + dr];
      }
    }
    // Th[b][row][ch][col]: fp16 store (64 B-contiguous per 32-lane group).
    #pragma unroll
    for (int j = 0; j < 8; ++j)
      Tp[(size_t)(tR0 + r0 + j) * TROW + tC0 + c] = __float2half(acc[j]);
  }
}

// ---------------------------------------------------------------------------
// k_mix v10: out = (W11 . T + 3*b11) * x.  EXACT v1 geometry -- 128 px x 64
// co per block, thread = 4 px x 8 co, acc[8][4] = 32 regs (HARD CAP: v5/v9
// both spilled with bigger acc), 3-slot ring, full unroll, no k-loop
// barriers, plain __launch_bounds__(256) -- with fp16 T: uint2 loads (8
// B/lane, 512 B/wave-instr), ring 48->24 VGPRs, T traffic halved (664->396
// MB total at the measured 5.2 TB/s BW-bound operating point).
// ---------------------------------------------------------------------------
__device__ __forceinline__ float2 h2f2(unsigned u) {
  return __half22float2(*reinterpret_cast<const __half2*>(&u));
}

__global__ __launch_bounds__(256) void k_mix(const __half* __restrict__ T,
                                             const float* __restrict__ x,
                                             const float* __restrict__ w11,
                                             const float* __restrict__ b11,
                                             float* __restrict__ out) {
  __shared__ float Wt[64 * 68];            // [ci][co], stride 68
  int bid = blockIdx.x;
  int b = bid >> 7;
  int row = bid & 127;
  int px0 = row * 128;
  int tid = threadIdx.x;

  for (int i = tid; i < 4096; i += 256) {
    int co = i >> 6, ci = i & 63;
    Wt[ci * 68 + co] = w11[i];
  }
  __syncthreads();

  int pxg = tid & 31;                      // 32 groups x 4 px
  int cog = tid >> 5;                      // 8 groups x 8 co
  // Th[b][row][ci][col]; thread's 4 px = 4 halves = 8 B per ci.
  const __half* Tb = T + (size_t)b * TBATCH + (size_t)row * TROW + pxg * 4;
  const float* wp = Wt + cog * 8;

  float acc[8][4];
  #pragma unroll
  for (int a = 0; a < 8; ++a)
    #pragma unroll
    for (int p = 0; p < 4; ++p) acc[a][p] = 0.f;

  uint2 tb[3][4];
  #pragma unroll
  for (int kk = 0; kk < 4; ++kk)
    tb[0][kk] = *(const uint2*)(Tb + (size_t)kk * 128);
  #pragma unroll
  for (int kk = 0; kk < 4; ++kk)
    tb[1][kk] = *(const uint2*)(Tb + (size_t)(4 + kk) * 128);

  #pragma unroll
  for (int kc = 0; kc < 16; ++kc) {
    const int cur = kc % 3;
    if (kc < 14) {
      const int nxt = (kc + 2) % 3;
      #pragma unroll
      for (int kk = 0; kk < 4; ++kk)
        tb[nxt][kk] =
            *(const uint2*)(Tb + (size_t)((kc + 2) * 4 + kk) * 128);
    }
    #pragma unroll
    for (int kk = 0; kk < 4; ++kk) {
      int k = kc * 4 + kk;
      float4 q0 = *(const float4*)(wp + k * 68);
      float4 q1 = *(const float4*)(wp + k * 68 + 4);
      float wf[8] = {q0.x, q0.y, q0.z, q0.w, q1.x, q1.y, q1.z, q1.w};
      uint2 tq = tb[cur][kk];
      float2 t0 = h2f2(tq.x), t1 = h2f2(tq.y);
      float tvv[4] = {t0.x, t0.y, t1.x, t1.y};
      #pragma unroll
      for (int a = 0; a < 8; ++a)
        #pragma unroll
        for (int p = 0; p < 4; ++p) acc[a][p] += wf[a] * tvv[p];
    }
  }

  const float* xb = x + (size_t)b * (CC * PLANE) + px0 + pxg * 4;
  float* ob = out + (size_t)b * (CC * PLANE) + px0 + pxg * 4;
  #pragma unroll
  for (int a = 0; a < 8; ++a) {
    int co = cog * 8 + a;
    float bb = 3.f * b11[co];
    float4 xv = *(const float4*)(xb + (size_t)co * PLANE);
    float4 o;
    o.x = (acc[a][0] + bb) * xv.x;
    o.y = (acc[a][1] + bb) * xv.y;
    o.z = (acc[a][2] + bb) * xv.z;
    o.w = (acc[a][3] + bb) * xv.w;
    *(float4*)(ob + (size_t)co * PLANE) = o;
  }
}

extern "C" void kernel_launch(void* const* d_in, const int* in_sizes, int n_in,
                              void* d_out, int out_size, void* d_ws,
                              size_t ws_size, hipStream_t stream) {
  const float* x = (const float*)d_in[0];
  const float* w55 = (const float*)d_in[1];
  const float* b55 = (const float*)d_in[2];
  const float* w17_0 = (const float*)d_in[3];
  const float* b17_0 = (const float*)d_in[4];
  const float* w17_1 = (const float*)d_in[5];
  const float* b17_1 = (const float*)d_in[6];
  const float* w111_0 = (const float*)d_in[7];
  const float* b111_0 = (const float*)d_in[8];
  const float* w111_1 = (const float*)d_in[9];
  const float* b111_1 = (const float*)d_in[10];
  const float* w211_0 = (const float*)d_in[11];
  const float* b211_0 = (const float*)d_in[12];
  const float* w211_1 = (const float*)d_in[13];
  const float* b211_1 = (const float*)d_in[14];
  const float* w11 = (const float*)d_in[15];
  const float* b11 = (const float*)d_in[16];
  float* outp = (float*)d_out;

  __half* T = (__half*)d_ws;               // Th[16][128][64][128] = 32 MB

  k_dwsum<<<BB * CC * 8, 256, 0, stream>>>(
      x, T, w55, b55, w17_0, b17_0, w17_1, b17_1, w111_0, b111_0, w111_1,
      b111_1, w211_0, b211_0, w211_1, b211_1);
  k_mix<<<BB * 128, 256, 0, stream>>>(T, x, w11, b11, outp);
}